// Round 1
// baseline (113.246 us; speedup 1.0000x reference)
//
#include <hip/hip_runtime.h>

#define BB 2
#define SS 128
#define HH 1024
#define AA 256
#define CC 14
#define R_TOT (BB*SS)   // 256 rows

struct NetP { const float *W1,*b1,*W2,*b2,*s0W,*s0b,*s1W,*s1b; };
struct AllP { NetP n[3]; };

// ws layout (floats)
#define S0_OFF 0                        // [3][256][14]
#define S1_OFF (3*R_TOT*CC)             // [3][256][14]
#define P_OFF  (2*3*R_TOT*CC)           // [2][129][14]
#define Q_OFF  (P_OFF + BB*(SS+1)*CC)
#define MEAN_OFF (Q_OFF + BB*(SS+1)*CC) // [2][14]

constexpr int ROWS = 8;  // rows per block (32 tiles per net, 3 nets -> 96 blocks)

// ---------------------------------------------------------------------------
// Kernel 1: per net, per 8-row tile: hid = relu(mem@W1+b1); out = hid@W2+b2;
// s0 = out@s0W+s0b; s1 = out@s1W+s1b.  K split across the 4 waves so each
// block reads W1/W2 exactly once; partials reduced via LDS.
// ---------------------------------------------------------------------------
__global__ __launch_bounds__(256)
void mlp_kernel(const float* __restrict__ mem, AllP P,
                float* __restrict__ s0o, float* __restrict__ s1o)
{
    const int net  = blockIdx.x >> 5;          // 0..2
    const int row0 = (blockIdx.x & 31) * ROWS; // 0..248
    const NetP p = P.n[net];
    const int lane = threadIdx.x & 63;
    const int wv   = __builtin_amdgcn_readfirstlane(threadIdx.x >> 6); // 0..3

    __shared__ float part[4][ROWS][AA];  // 32 KB
    __shared__ float hid[ROWS][AA];      // 8 KB
    __shared__ float outp[ROWS][AA];     // 8 KB

    // ---- layer 1: acc[r][u4] over k-quarter of this wave
    float acc[ROWS][4];
    #pragma unroll
    for (int r = 0; r < ROWS; ++r) { acc[r][0]=acc[r][1]=acc[r][2]=acc[r][3]=0.f; }
    {
        const int k0 = wv * (HH/4);
        #pragma unroll 4
        for (int k = k0; k < k0 + HH/4; ++k) {
            const float4 w = *(const float4*)(p.W1 + (size_t)k*AA + 4*lane);
            #pragma unroll
            for (int r = 0; r < ROWS; ++r) {
                const float m = mem[(size_t)(row0 + r)*HH + k];  // wave-uniform -> s_load
                acc[r][0] = fmaf(m, w.x, acc[r][0]);
                acc[r][1] = fmaf(m, w.y, acc[r][1]);
                acc[r][2] = fmaf(m, w.z, acc[r][2]);
                acc[r][3] = fmaf(m, w.w, acc[r][3]);
            }
        }
    }
    #pragma unroll
    for (int r = 0; r < ROWS; ++r)
        *(float4*)&part[wv][r][4*lane] = make_float4(acc[r][0],acc[r][1],acc[r][2],acc[r][3]);
    __syncthreads();
    for (int i = threadIdx.x; i < ROWS*AA; i += 256) {
        const int r = i >> 8, u = i & (AA-1);
        const float v = part[0][r][u]+part[1][r][u]+part[2][r][u]+part[3][r][u] + p.b1[u];
        hid[r][u] = fmaxf(v, 0.f);
    }
    __syncthreads();

    // ---- layer 2 (K = 256, quarter per wave)
    float acc2[ROWS][4];
    #pragma unroll
    for (int r = 0; r < ROWS; ++r) { acc2[r][0]=acc2[r][1]=acc2[r][2]=acc2[r][3]=0.f; }
    {
        const int k0 = wv * (AA/4);
        #pragma unroll 4
        for (int k = k0; k < k0 + AA/4; ++k) {
            const float4 w = *(const float4*)(p.W2 + (size_t)k*AA + 4*lane);
            #pragma unroll
            for (int r = 0; r < ROWS; ++r) {
                const float h = hid[r][k];   // uniform-address LDS broadcast
                acc2[r][0] = fmaf(h, w.x, acc2[r][0]);
                acc2[r][1] = fmaf(h, w.y, acc2[r][1]);
                acc2[r][2] = fmaf(h, w.z, acc2[r][2]);
                acc2[r][3] = fmaf(h, w.w, acc2[r][3]);
            }
        }
    }
    #pragma unroll
    for (int r = 0; r < ROWS; ++r)
        *(float4*)&part[wv][r][4*lane] = make_float4(acc2[r][0],acc2[r][1],acc2[r][2],acc2[r][3]);
    __syncthreads();
    for (int i = threadIdx.x; i < ROWS*AA; i += 256) {
        const int r = i >> 8, u = i & (AA-1);
        outp[r][u] = part[0][r][u]+part[1][r][u]+part[2][r][u]+part[3][r][u] + p.b2[u];
    }
    __syncthreads();

    // ---- projections to C=14: 2 mats * 8 rows * 14 cols = 224 dot products
    const int task = threadIdx.x;
    if (task < 2*ROWS*CC) {
        const int which = (task >= ROWS*CC) ? 1 : 0;
        const int rem   = task - which*ROWS*CC;
        const int r = rem / CC, c = rem % CC;
        const float* W = which ? p.s1W : p.s0W;
        float s = (which ? p.s1b : p.s0b)[c];
        #pragma unroll 4
        for (int k = 0; k < AA; ++k) s = fmaf(outp[r][k], W[k*CC + c], s);
        (which ? s1o : s0o)[(size_t)(net*R_TOT + row0 + r)*CC + c] = s;
    }
}

// ---------------------------------------------------------------------------
// Kernel 2: per (b,c): max over k of sm0, prefix sums of e=exp(sm0-M) and
// e*sm1, plus mean of sm1 (uniform-softmax case i>j).
// ---------------------------------------------------------------------------
__global__ __launch_bounds__(64)
void prefix_kernel(const float* __restrict__ s0w, const float* __restrict__ s1w,
                   float* __restrict__ Pp, float* __restrict__ Qp,
                   float* __restrict__ meanp)
{
    const int t = threadIdx.x;
    if (t >= BB*CC) return;
    const int b = t / CC, c = t % CC;
    const float* sm0 = s0w + (size_t)(2*R_TOT + b*SS)*CC + c;
    const float* sm1 = s1w + (size_t)(2*R_TOT + b*SS)*CC + c;
    float M = -3.4e38f;
    for (int k = 0; k < SS; ++k) M = fmaxf(M, sm0[k*CC]);
    float run = 0.f, runq = 0.f, ssum = 0.f;
    Pp[(size_t)(b*(SS+1))*CC + c] = 0.f;
    Qp[(size_t)(b*(SS+1))*CC + c] = 0.f;
    for (int k = 0; k < SS; ++k) {
        const float v1 = sm1[k*CC];
        const float e  = __expf(sm0[k*CC] - M);
        run += e; runq += e*v1; ssum += v1;
        Pp[(size_t)(b*(SS+1) + k + 1)*CC + c] = run;
        Qp[(size_t)(b*(SS+1) + k + 1)*CC + c] = runq;
    }
    meanp[b*CC + c] = ssum * (1.f/SS);
}

// ---------------------------------------------------------------------------
// Kernel 3: out[b,i,j,c] = sh1[b,i,c] + st1[b,j,c] + uni[c]
//   + (i<=j ? (Q[j+1]-Q[i])/(P[j+1]-P[i]) : mean[b,c])
// grid = B*S blocks (one per (b,i)), 128 threads = j
// ---------------------------------------------------------------------------
__global__ __launch_bounds__(128)
void final_kernel(const float* __restrict__ s1w,
                  const float* __restrict__ Pp, const float* __restrict__ Qp,
                  const float* __restrict__ meanp, const float* __restrict__ uni,
                  float* __restrict__ out)
{
    const int bi = blockIdx.x;        // b*S + i
    const int b = bi >> 7, i = bi & (SS-1);
    const int j = threadIdx.x;
    const float* sh1 = s1w + (size_t)(0*R_TOT + bi)*CC;            // uniform
    const float* st1 = s1w + (size_t)(1*R_TOT + b*SS + j)*CC;      // per-thread
    const float* Pb  = Pp + (size_t)b*(SS+1)*CC;
    const float* Qb  = Qp + (size_t)b*(SS+1)*CC;
    float* o = out + ((size_t)bi*SS + j)*CC;
    const bool tri = (i <= j);
    #pragma unroll
    for (int c = 0; c < CC; ++c) {
        float add;
        if (tri) {
            const float denom = Pb[(j+1)*CC + c] - Pb[i*CC + c];
            const float numer = Qb[(j+1)*CC + c] - Qb[i*CC + c];
            add = numer / denom;
        } else {
            add = meanp[b*CC + c];
        }
        o[c] = sh1[c] + st1[c] + uni[c] + add;
    }
}

extern "C" void kernel_launch(void* const* d_in, const int* in_sizes, int n_in,
                              void* d_out, int out_size, void* d_ws, size_t ws_size,
                              hipStream_t stream)
{
    const float* mem = (const float*)d_in[0];
    AllP P;
    for (int n = 0; n < 3; ++n) {
        const int base = 1 + 8*n;
        P.n[n].W1  = (const float*)d_in[base+0];
        P.n[n].b1  = (const float*)d_in[base+1];
        P.n[n].W2  = (const float*)d_in[base+2];
        P.n[n].b2  = (const float*)d_in[base+3];
        P.n[n].s0W = (const float*)d_in[base+4];
        P.n[n].s0b = (const float*)d_in[base+5];
        P.n[n].s1W = (const float*)d_in[base+6];
        P.n[n].s1b = (const float*)d_in[base+7];
    }
    const float* uni = (const float*)d_in[25];
    float* ws = (float*)d_ws;
    float* s0 = ws + S0_OFF;
    float* s1 = ws + S1_OFF;
    float* Pp = ws + P_OFF;
    float* Qp = ws + Q_OFF;
    float* mn = ws + MEAN_OFF;
    float* out = (float*)d_out;

    hipLaunchKernelGGL(mlp_kernel, dim3(96), dim3(256), 0, stream, mem, P, s0, s1);
    hipLaunchKernelGGL(prefix_kernel, dim3(1), dim3(64), 0, stream, s0, s1, Pp, Qp, mn);
    hipLaunchKernelGGL(final_kernel, dim3(BB*SS), dim3(SS), 0, stream, s1, Pp, Qp, mn, uni, out);
}

// Round 2
// 33.342 us; speedup vs baseline: 3.3965x; 3.3965x over previous
//
#include <hip/hip_runtime.h>

#define BB 2
#define SS 128
#define HH 1024
#define AA 256
#define CC 14
#define R_TOT (BB*SS)   // 256 rows per net

struct NetP { const float *W1,*b1,*W2,*b2,*s0W,*s0b,*s1W,*s1b; };
struct AllP { NetP n[3]; };

// ws layout (floats) — small stuff only; hid lives in d_out's tail
#define S0_OFF 0                        // [3][256][14]
#define S1_OFF (3*R_TOT*CC)             // [3][256][14]
#define P_OFF  (2*3*R_TOT*CC)           // [2][129][14]
#define Q_OFF  (P_OFF + BB*(SS+1)*CC)
#define MEAN_OFF (Q_OFF + BB*(SS+1)*CC) // [2][14]

// ---------------------------------------------------------------------------
// K1: hid[net][row][a] = relu(mem[row]·W1[:,a] + b1[a])
// grid = net(3) * rowtile(32 of 8 rows) * coltile(4 of 64 cols) = 384 blocks
// 512 threads = 8 waves; wave w handles K-chunk [w*128, w*128+128)
// mem reads are wave-uniform -> scalar loads; W1 reads coalesced.
// ---------------------------------------------------------------------------
__global__ __launch_bounds__(512)
void hid_kernel(const float* __restrict__ mem, AllP P, float* __restrict__ hid)
{
    const int bx  = blockIdx.x;
    const int net = bx >> 7;            // /128
    const int rem = bx & 127;
    const int rt  = rem >> 2;           // 0..31
    const int ct  = rem & 3;            // 0..3
    const int row0 = rt * 8;
    const int lane = threadIdx.x & 63;
    const int wv   = __builtin_amdgcn_readfirstlane(threadIdx.x >> 6); // 0..7
    const int col  = ct*64 + lane;
    const NetP p = P.n[net];

    __shared__ float part[8][8][64];    // [wave][row][lane] 16 KB

    float acc[8] = {0,0,0,0,0,0,0,0};
    const int k0 = wv * 128;
    const float* __restrict__ W1p  = p.W1 + (size_t)k0*AA + col;
    const float* __restrict__ memp = mem + (size_t)(net*0 + row0)*HH + k0;
    #pragma unroll 8
    for (int kk = 0; kk < 128; ++kk) {
        const float w = W1p[(size_t)kk*AA];
        #pragma unroll
        for (int r = 0; r < 8; ++r)
            acc[r] = fmaf(memp[(size_t)r*HH + kk], w, acc[r]);   // uniform -> s_load
    }
    #pragma unroll
    for (int r = 0; r < 8; ++r) part[wv][r][lane] = acc[r];
    __syncthreads();

    // 512 outputs (8 rows x 64 cols), one per thread
    const int r = threadIdx.x >> 6;
    const int l = threadIdx.x & 63;
    float s = p.b1[ct*64 + l];
    #pragma unroll
    for (int w = 0; w < 8; ++w) s += part[w][r][l];
    hid[((size_t)net*R_TOT + row0 + r)*AA + ct*64 + l] = fmaxf(s, 0.f);
}

// ---------------------------------------------------------------------------
// K2: outp = hid@W2 + b2 (4 rows/block, all 256 cols, K split 2-way), then
// fused projections s0 = outp@s0W+s0b, s1 = outp@s1W+s1b  (C=14)
// grid = net(3) * rowtile(64 of 4 rows) = 192 blocks, 512 threads
// ---------------------------------------------------------------------------
__global__ __launch_bounds__(512)
void out_kernel(const float* __restrict__ hid, AllP P,
                float* __restrict__ s0o, float* __restrict__ s1o)
{
    const int bx  = blockIdx.x;
    const int net = bx >> 6;
    const int rt  = bx & 63;
    const int row0 = rt * 4;
    const NetP p = P.n[net];
    const int col = threadIdx.x & 255;
    const int kh  = __builtin_amdgcn_readfirstlane(threadIdx.x >> 8); // 0/1

    __shared__ float part[2][4][256];   // 8 KB
    __shared__ float outp[4][256];      // 4 KB
    __shared__ float pp[112][4];        // 1.75 KB

    const float* __restrict__ hb = hid + ((size_t)net*R_TOT + row0)*AA;
    float acc[4] = {0,0,0,0};
    const int k0 = kh * 128;
    const float* __restrict__ W2p = p.W2 + (size_t)k0*AA + col;
    #pragma unroll 8
    for (int kk = 0; kk < 128; ++kk) {
        const float w = W2p[(size_t)kk*AA];
        #pragma unroll
        for (int r = 0; r < 4; ++r)
            acc[r] = fmaf(hb[(size_t)r*AA + k0 + kk], w, acc[r]);  // uniform -> s_load
    }
    #pragma unroll
    for (int r = 0; r < 4; ++r) part[kh][r][col] = acc[r];
    __syncthreads();

    for (int i = threadIdx.x; i < 4*AA; i += 512) {
        const int r = i >> 8, u = i & 255;
        outp[r][u] = part[0][r][u] + part[1][r][u] + p.b2[u];
    }
    __syncthreads();

    // projections: 112 (which,row,c) tasks x 4 K-chunks = 448 threads
    const int t = threadIdx.x;
    if (t < 448) {
        const int task = t >> 2, kc = t & 3;
        const int which = (task >= 56) ? 1 : 0;
        const int rem2  = task - which*56;
        const int rr = rem2 / CC, c = rem2 % CC;
        const float* __restrict__ W = which ? p.s1W : p.s0W;
        float s = 0.f;
        #pragma unroll 4
        for (int k = kc*64; k < kc*64 + 64; ++k)
            s = fmaf(outp[rr][k], W[(size_t)k*CC + c], s);
        pp[task][kc] = s;
    }
    __syncthreads();
    if (t < 112) {
        const int which = (t >= 56) ? 1 : 0;
        const int rem2  = t - which*56;
        const int rr = rem2 / CC, c = rem2 % CC;
        const float s = pp[t][0]+pp[t][1]+pp[t][2]+pp[t][3] + (which ? p.s1b : p.s0b)[c];
        (which ? s1o : s0o)[((size_t)net*R_TOT + row0 + rr)*CC + c] = s;
    }
}

// ---------------------------------------------------------------------------
// K3: per (b,c): M = max_k sm0; prefix sums of e=exp(sm0-M) and e*sm1;
// mean of sm1. Parallel: 28 blocks x 128 threads, shfl scan.
// ---------------------------------------------------------------------------
__global__ __launch_bounds__(128)
void prefix_kernel(const float* __restrict__ s0w, const float* __restrict__ s1w,
                   float* __restrict__ Pp, float* __restrict__ Qp,
                   float* __restrict__ meanp)
{
    const int b = blockIdx.x / CC, c = blockIdx.x % CC;
    const int k = threadIdx.x;                 // 0..127
    const int lane = k & 63, wv = k >> 6;
    const float x0 = s0w[(size_t)(2*R_TOT + b*SS + k)*CC + c];
    const float x1 = s1w[(size_t)(2*R_TOT + b*SS + k)*CC + c];
    __shared__ float smx[2], se[2], sq[2], ssm[2];

    float m = x0;
    #pragma unroll
    for (int off = 32; off >= 1; off >>= 1) m = fmaxf(m, __shfl_xor(m, off));
    float s1sum = x1;
    #pragma unroll
    for (int off = 32; off >= 1; off >>= 1) s1sum += __shfl_xor(s1sum, off);
    if (lane == 0) { smx[wv] = m; ssm[wv] = s1sum; }
    __syncthreads();
    const float M = fmaxf(smx[0], smx[1]);

    float e = __expf(x0 - M);
    float q = e * x1;
    #pragma unroll
    for (int off = 1; off <= 32; off <<= 1) {
        const float te = __shfl_up(e, off);
        const float tq = __shfl_up(q, off);
        if (lane >= off) { e += te; q += tq; }
    }
    if (lane == 63) { se[wv] = e; sq[wv] = q; }
    __syncthreads();
    if (wv == 1) { e += se[0]; q += sq[0]; }

    const size_t base = ((size_t)b*(SS+1))*CC + c;
    Pp[base + (size_t)(k+1)*CC] = e;
    Qp[base + (size_t)(k+1)*CC] = q;
    if (k == 0) {
        Pp[base] = 0.f;
        Qp[base] = 0.f;
        meanp[b*CC + c] = (ssm[0] + ssm[1]) * (1.f/SS);
    }
}

// ---------------------------------------------------------------------------
// K4: out[b,i,j,c] = sh1[b,i,c] + st1[b,j,c] + uni[c]
//    + (i<=j ? (Q[j+1]-Q[i])/(P[j+1]-P[i]) : mean[b,c])
// Flat idx = j*14+c matches st1/P/Q row-major layout -> fully coalesced.
// grid = 256 blocks ((b,i)), 512 threads
// ---------------------------------------------------------------------------
__global__ __launch_bounds__(512)
void final_kernel(const float* __restrict__ s1w,
                  const float* __restrict__ Pp, const float* __restrict__ Qp,
                  const float* __restrict__ meanp, const float* __restrict__ uni,
                  float* __restrict__ out)
{
    const int bi = blockIdx.x;        // b*S + i
    const int b = bi >> 7, i = bi & (SS-1);
    __shared__ float sh1L[CC], uniL[CC], mnL[CC], PiL[CC], QiL[CC];
    if (threadIdx.x < CC) {
        const int c = threadIdx.x;
        sh1L[c] = s1w[(size_t)bi*CC + c];                        // net h
        uniL[c] = uni[c];
        mnL[c]  = meanp[b*CC + c];
        PiL[c]  = Pp[((size_t)b*(SS+1) + i)*CC + c];
        QiL[c]  = Qp[((size_t)b*(SS+1) + i)*CC + c];
    }
    __syncthreads();
    const float* __restrict__ st1 = s1w + (size_t)(R_TOT + b*SS)*CC;  // [j][c]
    const float* __restrict__ Pj  = Pp + ((size_t)b*(SS+1) + 1)*CC;   // [j][c]
    const float* __restrict__ Qj  = Qp + ((size_t)b*(SS+1) + 1)*CC;
    float* __restrict__ o = out + (size_t)bi*SS*CC;
    for (int idx = threadIdx.x; idx < SS*CC; idx += 512) {
        const int j = idx / CC, c = idx - j*CC;
        float add;
        if (i <= j) add = (Qj[idx] - QiL[c]) / (Pj[idx] - PiL[c]);
        else        add = mnL[c];
        o[idx] = sh1L[c] + st1[idx] + uniL[c] + add;
    }
}

extern "C" void kernel_launch(void* const* d_in, const int* in_sizes, int n_in,
                              void* d_out, int out_size, void* d_ws, size_t ws_size,
                              hipStream_t stream)
{
    const float* mem = (const float*)d_in[0];
    AllP P;
    for (int n = 0; n < 3; ++n) {
        const int base = 1 + 8*n;
        P.n[n].W1  = (const float*)d_in[base+0];
        P.n[n].b1  = (const float*)d_in[base+1];
        P.n[n].W2  = (const float*)d_in[base+2];
        P.n[n].b2  = (const float*)d_in[base+3];
        P.n[n].s0W = (const float*)d_in[base+4];
        P.n[n].s0b = (const float*)d_in[base+5];
        P.n[n].s1W = (const float*)d_in[base+6];
        P.n[n].s1b = (const float*)d_in[base+7];
    }
    const float* uni = (const float*)d_in[25];
    float* ws = (float*)d_ws;
    float* s0 = ws + S0_OFF;
    float* s1 = ws + S1_OFF;
    float* Pp = ws + P_OFF;
    float* Qp = ws + Q_OFF;
    float* mn = ws + MEAN_OFF;
    float* out = (float*)d_out;
    // hid [3][256][256] f32 = 768 KB lives in d_out (1.8 MB); it is fully
    // consumed by out_kernel before final_kernel overwrites all of d_out.
    float* hid = out;

    hipLaunchKernelGGL(hid_kernel,    dim3(384),   dim3(512), 0, stream, mem, P, hid);
    hipLaunchKernelGGL(out_kernel,    dim3(192),   dim3(512), 0, stream, hid, P, s0, s1);
    hipLaunchKernelGGL(prefix_kernel, dim3(BB*CC), dim3(128), 0, stream, s0, s1, Pp, Qp, mn);
    hipLaunchKernelGGL(final_kernel,  dim3(BB*SS), dim3(512), 0, stream, s1, Pp, Qp, mn, uni, out);
}